// Round 3
// baseline (201516.711 us; speedup 1.0000x reference)
//
#include <hip/hip_runtime.h>
#include <stdint.h>

// dLSTM: L=2, H=2048, OUT=1024, B=64, T=256
// Persistent cooperative kernel: 256 blocks x 1024 threads, split
// arrive/wait grid barrier (latency hidden behind barrier-independent
// h-half GEMM). Weights fp32->bf16 + MFMA-native repack once per launch
// into d_ws (L3-resident; every wave B-load = 1KB contiguous), gates via
// mfma_f32_16x16x32_bf16 (fp32 accum), cell state resident in LDS.

#define NL   2
#define H    2048
#define FH   8192      // 4*H
#define NB   64        // batch
#define NOUT 1024
#define TT   256
#define NBLK 256
#define NTHR 1024
#define HB   131072    // NB*H elements (one h buffer)
#define WLAYER 16777216  // H*FH elements (one layer of Wih or Whh)

typedef __attribute__((ext_vector_type(4))) float f32x4;
typedef __attribute__((ext_vector_type(8))) short s16x8;

__device__ __forceinline__ short f2b(float f) {
    unsigned u = __builtin_bit_cast(unsigned, f);
    unsigned r = u + 0x7fffu + ((u >> 16) & 1u);   // round-to-nearest-even
    return (short)(r >> 16);
}

__global__ __launch_bounds__(NTHR, 4) void dlstm_kernel(
    const float* __restrict__ h0,  const float* __restrict__ c0,
    const float* __restrict__ Wih, const float* __restrict__ Whh,
    const float* __restrict__ bih, const float* __restrict__ bhh,
    const float* __restrict__ Wout,const float* __restrict__ bout,
    float* __restrict__ out,
    unsigned* __restrict__ bar,
    short* __restrict__ wih16, short* __restrict__ whh16,
    short* __restrict__ wout16, short* __restrict__ hbuf)
{
    __shared__ float gbuf[8][4][32][17];   // [ksplit][gate][row][col] 69.6 KB
    __shared__ float ybuf[16][16][17];     // [ksplit16][row][col]     17.4 KB
    __shared__ float clds[2][32][16];      // persistent cell state      4 KB
    __shared__ float blds[2][4][16];       // combined biases          512 B

    const int tid  = threadIdx.x;
    const int bid  = blockIdx.x;
    const int lane = tid & 63;
    const int wid  = tid >> 6;      // 0..15
    const int l15  = lane & 15;
    const int l4   = lane >> 4;

    const int mb = bid >> 7;        // batch half: rows mb*32..+32
    const int ug = bid & 127;       // unit group
    const int u0 = ug << 4;         // hidden unit base (16 units per block)
    const int ycg = bid >> 2;       // y col group 0..63
    const int yrb = bid & 3;        // y row group 0..3
    const int ks = wid >> 1;        // K split 0..7 (256-wide chunks)
    const int mt = wid & 1;         // M tile (16 rows)

    // ---------------- init: weight convert + MFMA-native repack ------------
    // Packed layout (per Wih/Whh): chunk c (16B = 8 bf16 = one lane-frag):
    //   lane=c&63, s=(c>>6)&7, ks=(c>>9)&7, g=(c>>12)&3, ug=(c>>14)&127,
    //   layer=c>>21.  Element offset = c*8.
    //   src row = g*H + ug*16 + (lane&15), col = ks*256 + (lane>>4)*8 + s*32.
    // => every wave B-load in the hot loop reads 1KB fully contiguous.
    {
        const int gtid = bid * NTHR + tid;
        const int GSTR = NBLK * NTHR;   // 262144
        auto cvt8 = [&](const float* sp) -> s16x8 {
            float4 v0 = *(const float4*)sp;
            float4 v1 = *(const float4*)(sp + 4);
            s16x8 o = { f2b(v0.x), f2b(v0.y), f2b(v0.z), f2b(v0.w),
                        f2b(v1.x), f2b(v1.y), f2b(v1.z), f2b(v1.w) };
            return o;
        };
        auto cvtW = [&](const float* src, short* dst) {  // both layers
            for (int c = gtid; c < 2 * WLAYER / 8; c += GSTR) {
                int ln = c & 63, r = c >> 6;
                int s = r & 7;   r >>= 3;
                int kk = r & 7;  r >>= 3;
                int g = r & 3;   r >>= 2;
                int u = r & 127; int layer = r >> 7;
                size_t row = (size_t)layer * FH + g * H + u * 16 + (ln & 15);
                int col = kk * 256 + (ln >> 4) * 8 + s * 32;
                *((s16x8*)dst + c) = cvt8(src + row * H + col);
            }
        };
        cvtW(Wih, wih16);
        cvtW(Whh, whh16);
        {   // Wout pack: lane=c&63, k=(c>>6)&3, w=(c>>8)&15, ycg=(c>>12)&63
            for (int c = gtid; c < NOUT * H / 8; c += GSTR) {
                int ln = c & 63, r = c >> 6;
                int k = r & 3;  r >>= 2;
                int w = r & 15; r >>= 4;
                int yc = r;     // 0..63
                size_t row = (size_t)yc * 16 + (ln & 15);
                int col = w * 128 + (ln >> 4) * 8 + k * 32;
                *((s16x8*)wout16 + c) = cvt8(Wout + row * H + col);
            }
        }
        // h buffers (parity 0) from h0: [L][B][H]; l=0 -> buf 0, l=1 -> buf 2
        for (int i = gtid; i < NL * NB * H; i += GSTR) {
            int l = i >> 17;
            int rem = i & (HB - 1);
            hbuf[(l * 2 + 0) * HB + rem] = f2b(h0[i]);
        }
        // cell state slice into LDS
        {
            int l = tid >> 9, row = (tid >> 4) & 31, col = tid & 15;
            clds[l][row][col] = c0[l * HB + (mb * 32 + row) * H + u0 + col];
        }
        // biases
        if (tid < 128) {
            int l = tid >> 6, g = (tid >> 4) & 3, c = tid & 15;
            blds[l][g][c] = bih[l * FH + g * H + u0 + c]
                          + bhh[l * FH + g * H + u0 + c];
        }
    }

    // -------- split grid barrier: arrive (signal) / bwait (spin) ----------
    unsigned bgen = 0;
    auto arrive = [&]() {
        __threadfence();                 // release stores to device scope
        __syncthreads();
        if (tid == 0) atomicAdd(&bar[(bid & 15) << 4], 1u);
        ++bgen;
    };
    auto bwait = [&]() {
        if (tid < 64) {
            const unsigned tgt = bgen * 16u;   // 16 blocks per counter line
            const int j = (lane & 15) << 4;
            while (true) {
                unsigned v = __hip_atomic_load(&bar[j], __ATOMIC_RELAXED,
                                               __HIP_MEMORY_SCOPE_AGENT);
                if (__all(v >= tgt)) break;
                __builtin_amdgcn_s_sleep(1);
            }
        }
        __syncthreads();
        __threadfence();                 // acquire: invalidate stale caches
    };

    // ---------------- per-wave GEMM state ----------------------------------
    f32x4 acc[4];                        // one 16x16 tile per gate
    s16x8 fr[8];                         // A fragments for this wave's K chunk

    auto zacc = [&]() {
        #pragma unroll
        for (int g = 0; g < 4; ++g) acc[g] = (f32x4){0.f, 0.f, 0.f, 0.f};
    };
    auto ldA = [&](const short* A) {      // preload 16 rows x 256 K as frags
        const short* p = A + (mb * 32 + mt * 16 + l15) * H + ks * 256 + l4 * 8;
        #pragma unroll
        for (int s = 0; s < 8; ++s) fr[s] = *(const s16x8*)(p + s * 32);
    };
    auto mmpart = [&](const short* Wp) {  // acc[g] += A @ W[g-slice]^T (packed)
        const short* base = Wp + ((size_t)(ug * 4) * 64 + ks * 8) * 512 + lane * 8;
        #pragma unroll
        for (int g = 0; g < 4; ++g) {
            const short* gp = base + (size_t)g * 64 * 512;
            #pragma unroll
            for (int s = 0; s < 8; ++s) {
                s16x8 b = *(const s16x8*)(gp + s * 512);
                acc[g] = __builtin_amdgcn_mfma_f32_16x16x32_bf16(fr[s], b, acc[g], 0, 0, 0);
            }
        }
    };
    auto storeg = [&]() {
        #pragma unroll
        for (int g = 0; g < 4; ++g)
            #pragma unroll
            for (int r = 0; r < 4; ++r)
                gbuf[ks][g][mt * 16 + l4 * 4 + r][l15] = acc[g][r];
    };

    auto cell_update = [&](int l, short* hout) {
        if (tid < 512) {
            int row = tid >> 4, col = tid & 15;
            float gv[4];
            #pragma unroll
            for (int g = 0; g < 4; ++g) {
                float s = blds[l][g][col];
                #pragma unroll
                for (int k = 0; k < 8; ++k) s += gbuf[k][g][row][col];
                gv[g] = s;
            }
            float co = clds[l][row][col];
            float si = 1.f / (1.f + __expf(-gv[0]));
            float sf = 1.f / (1.f + __expf(-gv[1]));
            float tg = tanhf(gv[2]);
            float so = 1.f / (1.f + __expf(-gv[3]));
            float cn = sf * co + si * tg;
            clds[l][row][col] = cn;
            hout[(mb * 32 + row) * H + u0 + col] = f2b(so * tanhf(cn));
        }
    };

    auto y_phase = [&](const short* h1prev) {   // 16-way K split, packed Wout
        const short* ap = h1prev + (yrb * 16 + l15) * H + wid * 128 + l4 * 8;
        const short* bp = wout16 + ((size_t)(ycg * 16 + wid) * 4) * 512 + lane * 8;
        f32x4 a2 = {0.f, 0.f, 0.f, 0.f};
        #pragma unroll
        for (int k = 0; k < 4; ++k) {
            s16x8 a = *(const s16x8*)(ap + k * 32);
            s16x8 b = *(const s16x8*)(bp + k * 512);
            a2 = __builtin_amdgcn_mfma_f32_16x16x32_bf16(a, b, a2, 0, 0, 0);
        }
        #pragma unroll
        for (int r = 0; r < 4; ++r) ybuf[wid][l4 * 4 + r][l15] = a2[r];
    };
    auto y_write = [&](int yidx) {
        if (tid >= 512 && tid < 768) {
            int e = tid - 512, row = e >> 4, col = e & 15;
            float s = bout[ycg * 16 + col];
            #pragma unroll
            for (int j = 0; j < 16; ++j) s += ybuf[j][row][col];
            out[((size_t)yidx * NB + yrb * 16 + row) * NOUT + ycg * 16 + col] = s;
        }
    };

    // ---------------- main time loop ---------------------------------------
    arrive(); bwait();                   // init barrier (weights/h visible)

    // prologue: h-half of layer 0 at t=0 (A = initial h0)
    zacc();
    ldA(hbuf + 0 * HB);
    mmpart(whh16);

    for (int t = 0; t < TT; ++t) {
        const int p = t & 1;
        const short* h1p = hbuf + (2 + p) * HB;        // h1_{t-1}
        short* h0n = hbuf + (p ^ 1) * HB;              // h0_t (to write)
        short* h1n = hbuf + (2 + (p ^ 1)) * HB;        // h1_t (to write)

        // x-half layer 0 (x = h1_{t-1}; zero at t=0)
        if (t > 0) { ldA(h1p); mmpart(wih16); }
        storeg();
        __syncthreads();
        cell_update(0, h0n);
        arrive();                                      // barrier A_t

        // barrier-A shadow: y_{t-1} + h-half of layer 1 (A = h1_{t-1})
        if (t > 0) y_phase(h1p);
        zacc();
        ldA(h1p);
        mmpart(whh16 + (size_t)WLAYER);
        bwait();                                       // h0_t now visible

        // x-half layer 1 (x = h0_t)
        ldA(h0n);
        mmpart(wih16 + (size_t)WLAYER);
        storeg();
        __syncthreads();
        cell_update(1, h1n);
        if (t > 0) y_write(t - 1);
        arrive();                                      // barrier B_t

        // barrier-B shadow: h-half of layer 0 for step t+1 (A = h0_t)
        zacc();
        ldA(h0n);
        mmpart(whh16);
        bwait();                                       // h1_t now visible
    }

    // epilogue: y_{T-1} from h1_{T-1} (write parity of t=255 -> buffer 2)
    y_phase(hbuf + 2 * HB);
    __syncthreads();
    y_write(TT - 1);
}

extern "C" void kernel_launch(void* const* d_in, const int* in_sizes, int n_in,
                              void* d_out, int out_size, void* d_ws, size_t ws_size,
                              hipStream_t stream) {
    const float* h0   = (const float*)d_in[0];
    const float* c0   = (const float*)d_in[1];
    const float* Wih  = (const float*)d_in[2];
    const float* Whh  = (const float*)d_in[3];
    const float* bih  = (const float*)d_in[4];
    const float* bhh  = (const float*)d_in[5];
    const float* Wout = (const float*)d_in[6];
    const float* bout = (const float*)d_in[7];
    float* out = (float*)d_out;

    char* ws = (char*)d_ws;
    unsigned* bar = (unsigned*)ws;                                   //   1 KB
    short* wih16  = (short*)(ws + 1024);                             //  64 MB
    short* whh16  = (short*)(ws + 1024 + 67108864);                  //  64 MB
    short* wout16 = (short*)(ws + 1024 + 2 * 67108864);              //   4 MB
    short* hbuf   = (short*)(ws + 1024 + 2 * 67108864 + 4194304);    //   1 MB
    // total ws use: ~139.5 MB

    hipMemsetAsync(bar, 0, 1024, stream);
    void* args[] = { &h0, &c0, &Wih, &Whh, &bih, &bhh, &Wout, &bout, &out,
                     &bar, &wih16, &whh16, &wout16, &hbuf };
    hipLaunchCooperativeKernel((void*)dlstm_kernel, dim3(NBLK), dim3(NTHR),
                               args, 0, stream);
}

// Round 4
// 122420.532 us; speedup vs baseline: 1.6461x; 1.6461x over previous
//
#include <hip/hip_runtime.h>
#include <stdint.h>

// dLSTM: L=2, H=2048, OUT=1024, B=64, T=256
// Persistent cooperative kernel: 256 blocks x 1024 threads.
// R3 lesson: old barrier = poll storm (every block 64-lane-gather polling 16
// device-scope lines every ~300ns -> ~800GB/s fabric congestion -> 200ms).
// New barrier: 32-line arrival counters + single checker block + replicated
// release flag, 1 lane/block polling with s_sleep backoff.
// Weights fp32->bf16 + MFMA-native repack once per launch into d_ws
// (every hot-loop B-load = 1KB contiguous), gates via mfma_f32_16x16x32_bf16,
// cell state resident in LDS, gate-ahead B-prefetch in registers.

#define NL   2
#define H    2048
#define FH   8192      // 4*H
#define NB   64        // batch
#define NOUT 1024
#define TT   256
#define NBLK 256
#define NTHR 1024
#define HB   131072    // NB*H elements (one h buffer)
#define WLAYER 16777216  // H*FH elements (one layer of Wih or Whh)

typedef __attribute__((ext_vector_type(4))) float f32x4;
typedef __attribute__((ext_vector_type(8))) short s16x8;

__device__ __forceinline__ short f2b(float f) {
    unsigned u = __builtin_bit_cast(unsigned, f);
    unsigned r = u + 0x7fffu + ((u >> 16) & 1u);   // round-to-nearest-even
    return (short)(r >> 16);
}

__global__ __launch_bounds__(NTHR, 4) void dlstm_kernel(
    const float* __restrict__ h0,  const float* __restrict__ c0,
    const float* __restrict__ Wih, const float* __restrict__ Whh,
    const float* __restrict__ bih, const float* __restrict__ bhh,
    const float* __restrict__ Wout,const float* __restrict__ bout,
    float* __restrict__ out,
    unsigned* __restrict__ bar,
    short* __restrict__ wih16, short* __restrict__ whh16,
    short* __restrict__ wout16, short* __restrict__ hbuf)
{
    __shared__ float gbuf[8][4][32][17];   // [ksplit][gate][row][col] 69.6 KB
    __shared__ float ybuf[16][16][17];     // [ksplit16][row][col]     17.4 KB
    __shared__ float clds[2][32][16];      // persistent cell state      4 KB
    __shared__ float blds[2][4][16];       // combined biases          512 B

    const int tid  = threadIdx.x;
    const int bid  = blockIdx.x;
    const int lane = tid & 63;
    const int wid  = tid >> 6;      // 0..15
    const int l15  = lane & 15;
    const int l4   = lane >> 4;

    const int mb = bid >> 7;        // batch half: rows mb*32..+32
    const int ug = bid & 127;       // unit group
    const int u0 = ug << 4;         // hidden unit base (16 units per block)
    const int ycg = bid >> 2;       // y col group 0..63
    const int yrb = bid & 3;        // y row group 0..3
    const int ks = wid >> 1;        // K split 0..7 (256-wide chunks)
    const int mt = wid & 1;         // M tile (16 rows)

    // ---------------- init: weight convert + MFMA-native repack ------------
    // Packed chunk c (16B = 8 bf16 = one lane-frag): lane=c&63, s=(c>>6)&7,
    // ks=(c>>9)&7, g=(c>>12)&3, ug=(c>>14)&127, layer=c>>21. elem off = c*8.
    // src row = layer*FH + g*H + ug*16 + (lane&15), col = ks*256+(lane>>4)*8+s*32.
    {
        const int gtid = bid * NTHR + tid;
        const int GSTR = NBLK * NTHR;   // 262144
        auto cvt8 = [&](const float* sp) -> s16x8 {
            float4 v0 = *(const float4*)sp;
            float4 v1 = *(const float4*)(sp + 4);
            s16x8 o = { f2b(v0.x), f2b(v0.y), f2b(v0.z), f2b(v0.w),
                        f2b(v1.x), f2b(v1.y), f2b(v1.z), f2b(v1.w) };
            return o;
        };
        auto cvtW = [&](const float* src, short* dst) {  // both layers
            for (int c = gtid; c < 2 * WLAYER / 8; c += GSTR) {
                int ln = c & 63, r = c >> 6;
                int s = r & 7;   r >>= 3;
                int kk = r & 7;  r >>= 3;
                int g = r & 3;   r >>= 2;
                int u = r & 127; int layer = r >> 7;
                size_t row = (size_t)layer * FH + g * H + u * 16 + (ln & 15);
                int col = kk * 256 + (ln >> 4) * 8 + s * 32;
                *((s16x8*)dst + c) = cvt8(src + row * H + col);
            }
        };
        cvtW(Wih, wih16);
        cvtW(Whh, whh16);
        {   // Wout pack: lane=c&63, k=(c>>6)&3, w=(c>>8)&15, ycg=(c>>12)&63
            for (int c = gtid; c < NOUT * H / 8; c += GSTR) {
                int ln = c & 63, r = c >> 6;
                int k = r & 3;  r >>= 2;
                int w = r & 15; r >>= 4;
                int yc = r;     // 0..63
                size_t row = (size_t)yc * 16 + (ln & 15);
                int col = w * 128 + (ln >> 4) * 8 + k * 32;
                *((s16x8*)wout16 + c) = cvt8(Wout + row * H + col);
            }
        }
        // h buffers (parity 0) from h0: [L][B][H]; l=0 -> buf 0, l=1 -> buf 2
        for (int i = gtid; i < NL * NB * H; i += GSTR) {
            int l = i >> 17;
            int rem = i & (HB - 1);
            hbuf[(l * 2 + 0) * HB + rem] = f2b(h0[i]);
        }
        // cell state slice into LDS
        {
            int l = tid >> 9, row = (tid >> 4) & 31, col = tid & 15;
            clds[l][row][col] = c0[l * HB + (mb * 32 + row) * H + u0 + col];
        }
        // biases
        if (tid < 128) {
            int l = tid >> 6, g = (tid >> 4) & 3, c = tid & 15;
            blds[l][g][c] = bih[l * FH + g * H + u0 + c]
                          + bhh[l * FH + g * H + u0 + c];
        }
    }

    // -------- split grid barrier: arrive / wait ---------------------------
    // arrival: 32 counter lines (bid&31), 8 blocks each.
    // release: block 0 wave 0 polls the 32 lines, then writes 8 replicated
    //          gen flags; other blocks poll 1 flag with 1 lane + s_sleep.
    unsigned bgen = 0;
    auto arrive = [&]() {
        __threadfence();                 // release h-writes to device scope
        __syncthreads();
        if (tid == 0) atomicAdd(&bar[(bid & 31) << 4], 1u);
        ++bgen;
    };
    auto bwait = [&]() {
        if (bid == 0) {
            if (tid < 64) {
                const unsigned tgt = bgen * 8u;    // 8 blocks per line
                while (true) {
                    unsigned v = tgt;
                    if (lane < 32)
                        v = __hip_atomic_load(&bar[lane << 4], __ATOMIC_RELAXED,
                                              __HIP_MEMORY_SCOPE_AGENT);
                    if (__all(v >= tgt)) break;
                    __builtin_amdgcn_s_sleep(2);
                }
                __threadfence();         // order counter reads before flags
                if (lane < 8)
                    __hip_atomic_store(&bar[1024 + (lane << 4)], bgen,
                                       __ATOMIC_RELAXED, __HIP_MEMORY_SCOPE_AGENT);
            }
        } else if (tid == 0) {
            const unsigned* fl = &bar[1024 + ((bid & 7) << 4)];
            while (__hip_atomic_load(fl, __ATOMIC_RELAXED,
                                     __HIP_MEMORY_SCOPE_AGENT) < bgen)
                __builtin_amdgcn_s_sleep(8);
        }
        __syncthreads();
        __threadfence();                 // acquire: invalidate stale caches
    };

    // ---------------- per-wave GEMM state ----------------------------------
    f32x4 acc[4];                        // one 16x16 tile per gate
    s16x8 fr[8];                         // A fragments for this wave's K chunk

    auto zacc = [&]() {
        #pragma unroll
        for (int g = 0; g < 4; ++g) acc[g] = (f32x4){0.f, 0.f, 0.f, 0.f};
    };
    auto ldA = [&](const short* A) {      // preload 16 rows x 256 K as frags
        const short* p = A + (mb * 32 + mt * 16 + l15) * H + ks * 256 + l4 * 8;
        #pragma unroll
        for (int s = 0; s < 8; ++s) fr[s] = *(const s16x8*)(p + s * 32);
    };
    auto mmpart = [&](const short* Wp) {  // acc[g] += A @ W[g-slice]^T (packed)
        const short* base = Wp + ((size_t)(ug * 4) * 64 + ks * 8) * 512 + lane * 8;
        s16x8 b0[8], b1[8];
        #pragma unroll
        for (int s = 0; s < 8; ++s) b0[s] = *(const s16x8*)(base + s * 512);
        #pragma unroll
        for (int g = 0; g < 4; ++g) {
            s16x8* cur = (g & 1) ? b1 : b0;
            s16x8* nxt = (g & 1) ? b0 : b1;
            if (g < 3) {                   // prefetch next gate's B frags
                const short* gp = base + (size_t)(g + 1) * 64 * 512;
                #pragma unroll
                for (int s = 0; s < 8; ++s) nxt[s] = *(const s16x8*)(gp + s * 512);
            }
            #pragma unroll
            for (int s = 0; s < 8; ++s)
                acc[g] = __builtin_amdgcn_mfma_f32_16x16x32_bf16(fr[s], cur[s], acc[g], 0, 0, 0);
        }
    };
    auto storeg = [&]() {
        #pragma unroll
        for (int g = 0; g < 4; ++g)
            #pragma unroll
            for (int r = 0; r < 4; ++r)
                gbuf[ks][g][mt * 16 + l4 * 4 + r][l15] = acc[g][r];
    };

    auto cell_update = [&](int l, short* hout) {
        if (tid < 512) {
            int row = tid >> 4, col = tid & 15;
            float gv[4];
            #pragma unroll
            for (int g = 0; g < 4; ++g) {
                float s = blds[l][g][col];
                #pragma unroll
                for (int k = 0; k < 8; ++k) s += gbuf[k][g][row][col];
                gv[g] = s;
            }
            float co = clds[l][row][col];
            float si = 1.f / (1.f + __expf(-gv[0]));
            float sf = 1.f / (1.f + __expf(-gv[1]));
            float tg = tanhf(gv[2]);
            float so = 1.f / (1.f + __expf(-gv[3]));
            float cn = sf * co + si * tg;
            clds[l][row][col] = cn;
            hout[(mb * 32 + row) * H + u0 + col] = f2b(so * tanhf(cn));
        }
    };

    auto y_phase = [&](const short* h1prev) {   // 16-way K split, packed Wout
        const short* ap = h1prev + (yrb * 16 + l15) * H + wid * 128 + l4 * 8;
        const short* bp = wout16 + ((size_t)(ycg * 16 + wid) * 4) * 512 + lane * 8;
        f32x4 a2 = {0.f, 0.f, 0.f, 0.f};
        #pragma unroll
        for (int k = 0; k < 4; ++k) {
            s16x8 a = *(const s16x8*)(ap + k * 32);
            s16x8 b = *(const s16x8*)(bp + k * 512);
            a2 = __builtin_amdgcn_mfma_f32_16x16x32_bf16(a, b, a2, 0, 0, 0);
        }
        #pragma unroll
        for (int r = 0; r < 4; ++r) ybuf[wid][l4 * 4 + r][l15] = a2[r];
    };
    auto y_write = [&](int yidx) {
        if (tid >= 512 && tid < 768) {
            int e = tid - 512, row = e >> 4, col = e & 15;
            float s = bout[ycg * 16 + col];
            #pragma unroll
            for (int j = 0; j < 16; ++j) s += ybuf[j][row][col];
            out[((size_t)yidx * NB + yrb * 16 + row) * NOUT + ycg * 16 + col] = s;
        }
    };

    // ---------------- main time loop ---------------------------------------
    arrive(); bwait();                   // init barrier (weights/h visible)

    // prologue: h-half of layer 0 at t=0 (A = initial h0)
    zacc();
    ldA(hbuf + 0 * HB);
    mmpart(whh16);

    for (int t = 0; t < TT; ++t) {
        const int p = t & 1;
        const short* h1p = hbuf + (2 + p) * HB;        // h1_{t-1}
        short* h0n = hbuf + (p ^ 1) * HB;              // h0_t (to write)
        short* h1n = hbuf + (2 + (p ^ 1)) * HB;        // h1_t (to write)

        // x-half layer 0 (x = h1_{t-1}; zero at t=0)
        if (t > 0) { ldA(h1p); mmpart(wih16); }
        storeg();
        __syncthreads();
        cell_update(0, h0n);
        arrive();                                      // barrier A_t

        // barrier-A shadow: y_{t-1} + h-half of layer 1 (A = h1_{t-1})
        if (t > 0) y_phase(h1p);
        zacc();
        ldA(h1p);
        mmpart(whh16 + (size_t)WLAYER);
        bwait();                                       // h0_t now visible

        // x-half layer 1 (x = h0_t)
        ldA(h0n);
        mmpart(wih16 + (size_t)WLAYER);
        storeg();
        __syncthreads();
        cell_update(1, h1n);
        if (t > 0) y_write(t - 1);
        arrive();                                      // barrier B_t

        // barrier-B shadow: h-half of layer 0 for step t+1 (A = h0_t)
        zacc();
        ldA(h0n);
        mmpart(whh16);
        bwait();                                       // h1_t now visible
    }

    // epilogue: y_{T-1} from h1_{T-1} (write parity of t=255 -> buffer 2)
    y_phase(hbuf + 2 * HB);
    __syncthreads();
    y_write(TT - 1);
}

extern "C" void kernel_launch(void* const* d_in, const int* in_sizes, int n_in,
                              void* d_out, int out_size, void* d_ws, size_t ws_size,
                              hipStream_t stream) {
    const float* h0   = (const float*)d_in[0];
    const float* c0   = (const float*)d_in[1];
    const float* Wih  = (const float*)d_in[2];
    const float* Whh  = (const float*)d_in[3];
    const float* bih  = (const float*)d_in[4];
    const float* bhh  = (const float*)d_in[5];
    const float* Wout = (const float*)d_in[6];
    const float* bout = (const float*)d_in[7];
    float* out = (float*)d_out;

    char* ws = (char*)d_ws;
    unsigned* bar = (unsigned*)ws;                                   //   8 KB
    short* wih16  = (short*)(ws + 8192);                             //  64 MB
    short* whh16  = (short*)(ws + 8192 + 67108864);                  //  64 MB
    short* wout16 = (short*)(ws + 8192 + 2 * 67108864);              //   4 MB
    short* hbuf   = (short*)(ws + 8192 + 2 * 67108864 + 4194304);    //   1 MB
    // total ws use: ~139.5 MB

    hipMemsetAsync(bar, 0, 8192, stream);
    void* args[] = { &h0, &c0, &Wih, &Whh, &bih, &bhh, &Wout, &bout, &out,
                     &bar, &wih16, &whh16, &wout16, &hbuf };
    hipLaunchCooperativeKernel((void*)dlstm_kernel, dim3(NBLK), dim3(NTHR),
                               args, 0, stream);
}